// Round 1
// baseline (153.922 us; speedup 1.0000x reference)
//
#include <hip/hip_runtime.h>
#include <hip/hip_bf16.h>

#define NTOK 8192
#define D_   1024
#define E_   8

#define MT 64
#define NT 128
#define BK 64
#define MAX_TILES 256

typedef __attribute__((ext_vector_type(8))) short short8;
typedef __attribute__((ext_vector_type(4))) float f32x4;

__device__ inline unsigned short f2b(float f) {
    unsigned int u = __float_as_uint(f);
    unsigned int r = (u + 0x7fffu + ((u >> 16) & 1u)) >> 16;
    return (unsigned short)r;
}

// ---------------- Phase 0: We (E,D,D) f32 -> WeT (E,M,D) bf16 ----------------
__global__ __launch_bounds__(256) void we_transpose(const float* __restrict__ We,
                                                    unsigned short* __restrict__ WeT) {
    int e = blockIdx.z;
    int m0 = blockIdx.x * 64;
    int d0 = blockIdx.y * 64;
    __shared__ float tile[64][65];
    const float* src = We + ((size_t)e << 20);
    int t = threadIdx.x;
    int r = t >> 4, c4 = (t & 15) * 4;
    #pragma unroll
    for (int i = 0; i < 4; i++) {
        int d = r + i * 16;
        float4 v = *reinterpret_cast<const float4*>(src + (size_t)(d0 + d) * D_ + m0 + c4);
        tile[d][c4 + 0] = v.x; tile[d][c4 + 1] = v.y;
        tile[d][c4 + 2] = v.z; tile[d][c4 + 3] = v.w;
    }
    __syncthreads();
    int m = t >> 2, dq = (t & 3) * 16;
    unsigned int pack[8];
    #pragma unroll
    for (int j = 0; j < 16; j += 2) {
        pack[j >> 1] = (unsigned int)f2b(tile[dq + j][m]) |
                       ((unsigned int)f2b(tile[dq + j + 1][m]) << 16);
    }
    uint4* dst = reinterpret_cast<uint4*>(WeT + ((size_t)e << 20) + (size_t)(m0 + m) * D_ + d0 + dq);
    dst[0] = make_uint4(pack[0], pack[1], pack[2], pack[3]);
    dst[1] = make_uint4(pack[4], pack[5], pack[6], pack[7]);
}

// ---------------- Phase 1: gating (top-2 + normalized weights) ----------------
__global__ __launch_bounds__(256) void gate_kernel(const float* __restrict__ x,
                                                   const float* __restrict__ Wg,
                                                   int* __restrict__ g_tok,
                                                   float* __restrict__ wA_tok,
                                                   float* __restrict__ wB_tok) {
    __shared__ float wgt[8 * 1024];   // transposed: wgt[e*1024 + d]
    int t = threadIdx.x;
    for (int i = t; i < 8192; i += 256) {
        int d = i >> 3, e = i & 7;
        wgt[e * 1024 + d] = Wg[i];
    }
    __syncthreads();
    int wave = t >> 6, lane = t & 63;
    int tok = blockIdx.x * 4 + wave;
    const float* xr = x + (size_t)tok * D_;
    float acc[8] = {0.f, 0.f, 0.f, 0.f, 0.f, 0.f, 0.f, 0.f};
    for (int i = 0; i < 16; i++) {
        int d = i * 64 + lane;
        float xv = xr[d];
        #pragma unroll
        for (int e = 0; e < 8; e++) acc[e] += xv * wgt[e * 1024 + d];
    }
    #pragma unroll
    for (int e = 0; e < 8; e++) {
        #pragma unroll
        for (int off = 32; off > 0; off >>= 1)
            acc[e] += __shfl_xor(acc[e], off, 64);
    }
    if (lane == 0) {
        float best = acc[0]; int bi = 0;
        #pragma unroll
        for (int e = 1; e < 8; e++) { if (acc[e] > best) { best = acc[e]; bi = e; } }
        float second = -3.4e38f; int si = 0;
        #pragma unroll
        for (int e = 0; e < 8; e++) {
            if (e != bi && acc[e] > second) { second = acc[e]; si = e; }
        }
        float eb = __expf(second - best);
        float w0 = 1.f / (1.f + eb);   // weight of best
        float w1 = eb / (1.f + eb);    // weight of second
        int a, b; float wA, wB;
        if (bi < si) { a = bi; b = si; wA = w0; wB = w1; }
        else         { a = si; b = bi; wA = w1; wB = w0; }
        g_tok[tok] = a * 8 + b;
        wA_tok[tok] = wA;
        wB_tok[tok] = wB;
    }
}

// ---------------- Phase 2: routing (bucket by expert pair + tile schedule) ----------------
__global__ __launch_bounds__(1024) void route_kernel(const int* __restrict__ g_tok,
                                                     const float* __restrict__ wA_tok,
                                                     const float* __restrict__ wB_tok,
                                                     int* __restrict__ token_list,
                                                     float* __restrict__ wA_s,
                                                     float* __restrict__ wB_s,
                                                     int4* __restrict__ tile_desc,
                                                     int* __restrict__ n_tiles_out) {
    __shared__ int cnt[64], pos[64], start[64];
    int t = threadIdx.x;
    if (t < 64) cnt[t] = 0;
    __syncthreads();
    for (int i = t; i < NTOK; i += 1024) atomicAdd(&cnt[g_tok[i]], 1);
    __syncthreads();
    if (t == 0) {
        int run = 0, nt = 0;
        for (int g = 0; g < 64; g++) {
            start[g] = run;
            int c = cnt[g];
            int off = 0;
            while (off < c) {
                int rows = (c - off < MT) ? (c - off) : MT;
                tile_desc[nt++] = make_int4(run + off, rows, g >> 3, g & 7);
                off += MT;
            }
            run += c;
        }
        *n_tiles_out = nt;
    }
    __syncthreads();
    if (t < 64) pos[t] = start[t];
    __syncthreads();
    for (int i = t; i < NTOK; i += 1024) {
        int g = g_tok[i];
        int p = atomicAdd(&pos[g], 1);
        token_list[p] = i;
        wA_s[p] = wA_tok[i];
        wB_s[p] = wB_tok[i];
    }
}

// ---------------- Phase 3: grouped GEMM (pair tiles, bf16 MFMA) ----------------
__global__ __launch_bounds__(256, 2) void moe_gemm(const float* __restrict__ x,
                                                   const unsigned short* __restrict__ WeT,
                                                   const int* __restrict__ token_list,
                                                   const float* __restrict__ wA_s,
                                                   const float* __restrict__ wB_s,
                                                   const int4* __restrict__ tile_desc,
                                                   const int* __restrict__ n_tiles,
                                                   float* __restrict__ out) {
    int tile = blockIdx.y;
    if (tile >= *n_tiles) return;
    int4 dsc = tile_desc[tile];
    int loff = dsc.x, rows = dsc.y, ea = dsc.z, ebx = dsc.w;
    int ncol0 = blockIdx.x * NT;

    __shared__ unsigned short Al[2][MT][72];
    __shared__ unsigned short Bl[2][NT][72];
    __shared__ int toks[MT];
    __shared__ float wAs[MT], wBs[MT];

    int t = threadIdx.x;
    if (t < MT) {
        if (t < rows) {
            toks[t] = token_list[loff + t];
            wAs[t] = wA_s[loff + t];
            wBs[t] = wB_s[loff + t];
        } else {
            toks[t] = 0; wAs[t] = 0.f; wBs[t] = 0.f;
        }
    }
    __syncthreads();

    const unsigned short* wea = WeT + ((size_t)ea << 20);
    const unsigned short* web = WeT + ((size_t)ebx << 20);

    int wave = t >> 6, lane = t & 63;
    int wm = (wave & 1) * 32, wn = (wave >> 1) * 64;

    // A staging role: 4 threads per row, 16 k-elems each
    int ar = t >> 2, akq = (t & 3) * 16;
    const float* xrow = x + (size_t)toks[ar] * D_ + akq;
    float wa_r = wAs[ar], wb_r = wBs[ar];
    // B staging role: 8 threads per n-row (16B each), 32 rows per pass
    int bj = t & 7, br0 = t >> 3;

    f32x4 acc[2][4];
    #pragma unroll
    for (int i = 0; i < 2; i++)
        #pragma unroll
        for (int j = 0; j < 4; j++) acc[i][j] = (f32x4){0.f, 0.f, 0.f, 0.f};

    for (int k0 = 0; k0 < D_; k0 += BK) {
        // ---- stage A (gather + weight-scale + f32->bf16), both experts ----
        const float* xp = xrow + k0;
        #pragma unroll
        for (int i = 0; i < 4; i++) {
            float4 v = *reinterpret_cast<const float4*>(xp + i * 4);
            ushort4 ua = make_ushort4(f2b(v.x * wa_r), f2b(v.y * wa_r),
                                      f2b(v.z * wa_r), f2b(v.w * wa_r));
            ushort4 ub = make_ushort4(f2b(v.x * wb_r), f2b(v.y * wb_r),
                                      f2b(v.z * wb_r), f2b(v.w * wb_r));
            *reinterpret_cast<ushort4*>(&Al[0][ar][akq + i * 4]) = ua;
            *reinterpret_cast<ushort4*>(&Al[1][ar][akq + i * 4]) = ub;
        }
        // ---- stage B (bf16, contiguous 16B chunks from WeT) ----
        #pragma unroll
        for (int p = 0; p < 8; p++) {
            int rid = br0 + p * 32;
            int e = rid >> 7, n = rid & 127;
            const unsigned short* wp = (e ? web : wea) +
                (size_t)(ncol0 + n) * D_ + k0 + bj * 8;
            *reinterpret_cast<uint4*>(&Bl[e][n][bj * 8]) =
                *reinterpret_cast<const uint4*>(wp);
        }
        __syncthreads();
        // ---- MFMA ----
        #pragma unroll
        for (int kk = 0; kk < BK; kk += 32) {
            int kf = kk + (lane >> 4) * 8;
            int rA0 = wm + (lane & 15), rA1 = wm + 16 + (lane & 15);
            short8 a00 = *reinterpret_cast<const short8*>(&Al[0][rA0][kf]);
            short8 a01 = *reinterpret_cast<const short8*>(&Al[0][rA1][kf]);
            short8 a10 = *reinterpret_cast<const short8*>(&Al[1][rA0][kf]);
            short8 a11 = *reinterpret_cast<const short8*>(&Al[1][rA1][kf]);
            #pragma unroll
            for (int ni = 0; ni < 4; ni++) {
                int cB = wn + ni * 16 + (lane & 15);
                short8 b0 = *reinterpret_cast<const short8*>(&Bl[0][cB][kf]);
                short8 b1 = *reinterpret_cast<const short8*>(&Bl[1][cB][kf]);
                acc[0][ni] = __builtin_amdgcn_mfma_f32_16x16x32_bf16(a00, b0, acc[0][ni], 0, 0, 0);
                acc[0][ni] = __builtin_amdgcn_mfma_f32_16x16x32_bf16(a10, b1, acc[0][ni], 0, 0, 0);
                acc[1][ni] = __builtin_amdgcn_mfma_f32_16x16x32_bf16(a01, b0, acc[1][ni], 0, 0, 0);
                acc[1][ni] = __builtin_amdgcn_mfma_f32_16x16x32_bf16(a11, b1, acc[1][ni], 0, 0, 0);
            }
        }
        __syncthreads();
    }

    // ---- epilogue: each token row written exactly once, weights already folded in ----
    int q4 = (lane >> 4) * 4, c = lane & 15;
    #pragma unroll
    for (int mi = 0; mi < 2; mi++) {
        #pragma unroll
        for (int ni = 0; ni < 4; ni++) {
            int col = ncol0 + wn + ni * 16 + c;
            #pragma unroll
            for (int j = 0; j < 4; j++) {
                int r = wm + mi * 16 + q4 + j;
                if (r < rows) out[(size_t)toks[r] * D_ + col] = acc[mi][ni][j];
            }
        }
    }
}

extern "C" void kernel_launch(void* const* d_in, const int* in_sizes, int n_in,
                              void* d_out, int out_size, void* d_ws, size_t ws_size,
                              hipStream_t stream) {
    const float* x  = (const float*)d_in[0];
    const float* Wg = (const float*)d_in[1];
    const float* We = (const float*)d_in[2];
    float* out = (float*)d_out;

    size_t off = 0;
    auto alloc = [&](size_t bytes) -> void* {
        void* p = (char*)d_ws + off;
        off += (bytes + 255) & ~(size_t)255;
        return p;
    };
    unsigned short* WeT = (unsigned short*)alloc((size_t)E_ * 1024 * 1024 * 2);
    int*   g_tok     = (int*)  alloc(NTOK * 4);
    float* wA_tok    = (float*)alloc(NTOK * 4);
    float* wB_tok    = (float*)alloc(NTOK * 4);
    int*   token_list= (int*)  alloc(NTOK * 4);
    float* wA_s      = (float*)alloc(NTOK * 4);
    float* wB_s      = (float*)alloc(NTOK * 4);
    int4*  tile_desc = (int4*) alloc(MAX_TILES * 16);
    int*   n_tiles   = (int*)  alloc(4);

    we_transpose<<<dim3(16, 16, 8), 256, 0, stream>>>(We, WeT);
    gate_kernel<<<NTOK / 4, 256, 0, stream>>>(x, Wg, g_tok, wA_tok, wB_tok);
    route_kernel<<<1, 1024, 0, stream>>>(g_tok, wA_tok, wB_tok,
                                         token_list, wA_s, wB_s, tile_desc, n_tiles);
    moe_gemm<<<dim3(D_ / NT, MAX_TILES), 256, 0, stream>>>(x, WeT, token_list, wA_s, wB_s,
                                                           tile_desc, n_tiles, out);
}

// Round 2
// 142.226 us; speedup vs baseline: 1.0822x; 1.0822x over previous
//
#include <hip/hip_runtime.h>
#include <hip/hip_bf16.h>
#include <stdint.h>

#define NTOK 8192
#define D_   1024
#define E_   8
#define MT   64
#define NT   256
#define BK   32
#define KK   2048
#define MAX_TILES 192

typedef __attribute__((ext_vector_type(8))) short short8;
typedef __attribute__((ext_vector_type(4))) float f32x4;

__device__ inline unsigned short f2b(float f) {
    unsigned int u = __float_as_uint(f);
    unsigned int r = (u + 0x7fffu + ((u >> 16) & 1u)) >> 16;
    return (unsigned short)r;
}

// async global->LDS, 16B per lane. LDS dest must be wave-uniform base; HW adds lane*16.
__device__ inline void gload16(const void* g, void* l) {
    __builtin_amdgcn_global_load_lds(
        (const __attribute__((address_space(1))) unsigned int*)(uintptr_t)g,
        (__attribute__((address_space(3))) unsigned int*)(unsigned int)(uintptr_t)l,
        16, 0, 0);
}

// ---------------- Phase 0: We (E,D,D) f32 -> WeT (E,M,D) bf16 ----------------
__global__ __launch_bounds__(256) void we_transpose(const float* __restrict__ We,
                                                    unsigned short* __restrict__ WeT) {
    int e = blockIdx.z;
    int m0 = blockIdx.x * 64;
    int d0 = blockIdx.y * 64;
    __shared__ float tile[64][65];
    const float* src = We + ((size_t)e << 20);
    int t = threadIdx.x;
    int r = t >> 4, c4 = (t & 15) * 4;
    #pragma unroll
    for (int i = 0; i < 4; i++) {
        int d = r + i * 16;
        float4 v = *reinterpret_cast<const float4*>(src + (size_t)(d0 + d) * D_ + m0 + c4);
        tile[d][c4 + 0] = v.x; tile[d][c4 + 1] = v.y;
        tile[d][c4 + 2] = v.z; tile[d][c4 + 3] = v.w;
    }
    __syncthreads();
    int m = t >> 2, dq = (t & 3) * 16;
    unsigned int pack[8];
    #pragma unroll
    for (int j = 0; j < 16; j += 2) {
        pack[j >> 1] = (unsigned int)f2b(tile[dq + j][m]) |
                       ((unsigned int)f2b(tile[dq + j + 1][m]) << 16);
    }
    uint4* dst = reinterpret_cast<uint4*>(WeT + ((size_t)e << 20) + (size_t)(m0 + m) * D_ + d0 + dq);
    dst[0] = make_uint4(pack[0], pack[1], pack[2], pack[3]);
    dst[1] = make_uint4(pack[4], pack[5], pack[6], pack[7]);
}

// ---------------- Phase 1: gating (top-2 + normalized weights) ----------------
__global__ __launch_bounds__(256) void gate_kernel(const float* __restrict__ x,
                                                   const float* __restrict__ Wg,
                                                   int* __restrict__ g_tok,
                                                   float* __restrict__ wA_tok,
                                                   float* __restrict__ wB_tok) {
    __shared__ float wgt[8 * 1024];   // transposed: wgt[e*1024 + d]
    int t = threadIdx.x;
    for (int i = t; i < 8192; i += 256) {
        int d = i >> 3, e = i & 7;
        wgt[e * 1024 + d] = Wg[i];
    }
    __syncthreads();
    int wave = t >> 6, lane = t & 63;
    int tok = blockIdx.x * 4 + wave;
    const float* xr = x + (size_t)tok * D_;
    float acc[8] = {0.f, 0.f, 0.f, 0.f, 0.f, 0.f, 0.f, 0.f};
    for (int i = 0; i < 16; i++) {
        int d = i * 64 + lane;
        float xv = xr[d];
        #pragma unroll
        for (int e = 0; e < 8; e++) acc[e] += xv * wgt[e * 1024 + d];
    }
    #pragma unroll
    for (int e = 0; e < 8; e++) {
        #pragma unroll
        for (int off = 32; off > 0; off >>= 1)
            acc[e] += __shfl_xor(acc[e], off, 64);
    }
    if (lane == 0) {
        float best = acc[0]; int bi = 0;
        #pragma unroll
        for (int e = 1; e < 8; e++) { if (acc[e] > best) { best = acc[e]; bi = e; } }
        float second = -3.4e38f; int si = 0;
        #pragma unroll
        for (int e = 0; e < 8; e++) {
            if (e != bi && acc[e] > second) { second = acc[e]; si = e; }
        }
        float eb = __expf(second - best);
        float w0 = 1.f / (1.f + eb);   // weight of best
        float w1 = eb / (1.f + eb);    // weight of second
        int a, b; float wA, wB;
        if (bi < si) { a = bi; b = si; wA = w0; wB = w1; }
        else         { a = si; b = bi; wA = w1; wB = w0; }
        g_tok[tok] = a * 8 + b;
        wA_tok[tok] = wA;
        wB_tok[tok] = wB;
    }
}

// ---------------- Phase 2: routing (bucket by expert pair + tile schedule) ----------------
__global__ __launch_bounds__(1024) void route_kernel(const int* __restrict__ g_tok,
                                                     const float* __restrict__ wA_tok,
                                                     const float* __restrict__ wB_tok,
                                                     int* __restrict__ token_list,
                                                     float* __restrict__ wA_s,
                                                     float* __restrict__ wB_s,
                                                     int4* __restrict__ tile_desc,
                                                     int* __restrict__ n_tiles_out) {
    __shared__ int cnt[64], pos[64], start[64];
    int t = threadIdx.x;
    if (t < 64) cnt[t] = 0;
    __syncthreads();
    for (int i = t; i < NTOK; i += 1024) atomicAdd(&cnt[g_tok[i]], 1);
    __syncthreads();
    if (t == 0) {
        int run = 0, nt = 0;
        for (int g = 0; g < 64; g++) {
            start[g] = run;
            int c = cnt[g];
            int off = 0;
            while (off < c) {
                int rows = (c - off < MT) ? (c - off) : MT;
                tile_desc[nt++] = make_int4(run + off, rows, g >> 3, g & 7);
                off += MT;
            }
            run += c;
        }
        *n_tiles_out = nt;
    }
    __syncthreads();
    if (t < 64) pos[t] = start[t];
    __syncthreads();
    for (int i = t; i < NTOK; i += 1024) {
        int g = g_tok[i];
        int p = atomicAdd(&pos[g], 1);
        token_list[p] = i;
        wA_s[p] = wA_tok[i];
        wB_s[p] = wB_tok[i];
    }
}

// ---------------- Phase 2.5: cast/gather x into sorted, weight-folded bf16 A ----------------
// Abf[slot][0:1024]   = bf16(x[tok] * wA)   (expert a half)
// Abf[slot][1024:2048]= bf16(x[tok] * wB)   (expert b half)
__global__ __launch_bounds__(256) void cast_kernel(const float* __restrict__ x,
                                                   const int* __restrict__ token_list,
                                                   const float* __restrict__ wA_s,
                                                   const float* __restrict__ wB_s,
                                                   unsigned short* __restrict__ Abf) {
    int s = blockIdx.x;
    int tok = token_list[s];
    float wa = wA_s[s], wb = wB_s[s];
    int t = threadIdx.x;
    float4 v = *reinterpret_cast<const float4*>(x + (size_t)tok * D_ + t * 4);
    ushort4 ua = make_ushort4(f2b(v.x * wa), f2b(v.y * wa), f2b(v.z * wa), f2b(v.w * wa));
    ushort4 ub = make_ushort4(f2b(v.x * wb), f2b(v.y * wb), f2b(v.z * wb), f2b(v.w * wb));
    unsigned short* row = Abf + (size_t)s * KK;
    *reinterpret_cast<ushort4*>(row + t * 4) = ua;
    *reinterpret_cast<ushort4*>(row + D_ + t * 4) = ub;
}

// ---------------- Phase 3: grouped GEMM, m97 structure (global_load_lds, K=2048) ----------------
__global__ __launch_bounds__(256) void moe_gemm(const unsigned short* __restrict__ Abf,
                                                const unsigned short* __restrict__ WeT,
                                                const int* __restrict__ token_list,
                                                const int4* __restrict__ tile_desc,
                                                const int* __restrict__ n_tiles,
                                                float* __restrict__ out) {
    int tile = blockIdx.y;
    if (tile >= *n_tiles) return;
    int4 dsc = tile_desc[tile];
    int loff = dsc.x, rows = dsc.y;
    const unsigned short* wa_base = WeT + ((size_t)dsc.z << 20);
    const unsigned short* wb_base = WeT + ((size_t)dsc.w << 20);
    int ncol0 = blockIdx.x * NT;

    __shared__ __align__(16) unsigned short As[MT * BK];   // 4 KB, [64][32]
    __shared__ __align__(16) unsigned short Bs[NT * BK];   // 16 KB, [256][32]
    __shared__ int tokl[MT];

    int t = threadIdx.x;
    int wave = t >> 6, lane = t & 63;

    if (t < MT) tokl[t] = (t < rows) ? token_list[loff + t] : -1;

    // A staging: one round. chunk = t; row = chunk>>2, 16B k-chunk = chunk&3
    int arow = t >> 2;
    int aka = (t & 3) * 8;
    int arc = arow < rows ? arow : rows - 1;          // clamp pad rows to valid data
    const unsigned short* asrc = Abf + (size_t)(loff + arc) * KK + aka;
    unsigned short* adst = &As[(wave * 64) * 8];      // wave-uniform

    // B staging: four rounds. chunk = i*256 + t
    int brow[4], bka[4];
    unsigned short* bdst[4];
    #pragma unroll
    for (int i = 0; i < 4; i++) {
        int chunk = i * 256 + t;
        brow[i] = chunk >> 2;
        bka[i] = (chunk & 3) * 8;
        bdst[i] = &Bs[(i * 256 + wave * 64) * 8];
    }

    f32x4 acc[4][4];
    #pragma unroll
    for (int m = 0; m < 4; m++)
        #pragma unroll
        for (int n = 0; n < 4; n++) acc[m][n] = (f32x4){0.f, 0.f, 0.f, 0.f};

    for (int k0 = 0; k0 < KK; k0 += BK) {
        const unsigned short* wb = (k0 < D_) ? wa_base : wb_base;  // expert half (wave-uniform)
        int kloc = k0 & (D_ - 1);
        gload16(asrc + k0, adst);
        #pragma unroll
        for (int i = 0; i < 4; i++)
            gload16(wb + (size_t)(ncol0 + brow[i]) * D_ + kloc + bka[i], bdst[i]);
        __syncthreads();

        int kf = (lane >> 4) * 8;
        short8 a[4], b[4];
        #pragma unroll
        for (int m = 0; m < 4; m++)
            a[m] = *reinterpret_cast<const short8*>(&As[(m * 16 + (lane & 15)) * BK + kf]);
        #pragma unroll
        for (int n = 0; n < 4; n++)
            b[n] = *reinterpret_cast<const short8*>(&Bs[(wave * 64 + n * 16 + (lane & 15)) * BK + kf]);
        #pragma unroll
        for (int m = 0; m < 4; m++)
            #pragma unroll
            for (int n = 0; n < 4; n++)
                acc[m][n] = __builtin_amdgcn_mfma_f32_16x16x32_bf16(a[m], b[n], acc[m][n], 0, 0, 0);
        __syncthreads();
    }

    // epilogue: single writer per out row, weights already folded in
    int q4 = (lane >> 4) * 4, c = lane & 15;
    #pragma unroll
    for (int m = 0; m < 4; m++) {
        #pragma unroll
        for (int n = 0; n < 4; n++) {
            int col = ncol0 + wave * 64 + n * 16 + c;
            #pragma unroll
            for (int j = 0; j < 4; j++) {
                int r = m * 16 + q4 + j;
                int tk = tokl[r];
                if (tk >= 0) out[(size_t)tk * D_ + col] = acc[m][n][j];
            }
        }
    }
}

extern "C" void kernel_launch(void* const* d_in, const int* in_sizes, int n_in,
                              void* d_out, int out_size, void* d_ws, size_t ws_size,
                              hipStream_t stream) {
    const float* x  = (const float*)d_in[0];
    const float* Wg = (const float*)d_in[1];
    const float* We = (const float*)d_in[2];
    float* out = (float*)d_out;

    size_t off = 0;
    auto alloc = [&](size_t bytes) -> void* {
        void* p = (char*)d_ws + off;
        off += (bytes + 255) & ~(size_t)255;
        return p;
    };
    unsigned short* WeT  = (unsigned short*)alloc((size_t)E_ * 1024 * 1024 * 2);  // 16 MB
    unsigned short* Abf  = (unsigned short*)alloc((size_t)NTOK * KK * 2);         // 33.5 MB
    int*   g_tok      = (int*)  alloc(NTOK * 4);
    float* wA_tok     = (float*)alloc(NTOK * 4);
    float* wB_tok     = (float*)alloc(NTOK * 4);
    int*   token_list = (int*)  alloc(NTOK * 4);
    float* wA_s       = (float*)alloc(NTOK * 4);
    float* wB_s       = (float*)alloc(NTOK * 4);
    int4*  tile_desc  = (int4*) alloc(MAX_TILES * 16);
    int*   n_tiles    = (int*)  alloc(4);

    we_transpose<<<dim3(16, 16, 8), 256, 0, stream>>>(We, WeT);
    gate_kernel<<<NTOK / 4, 256, 0, stream>>>(x, Wg, g_tok, wA_tok, wB_tok);
    route_kernel<<<1, 1024, 0, stream>>>(g_tok, wA_tok, wB_tok,
                                         token_list, wA_s, wB_s, tile_desc, n_tiles);
    cast_kernel<<<NTOK, 256, 0, stream>>>(x, token_list, wA_s, wB_s, Abf);
    moe_gemm<<<dim3(D_ / NT, MAX_TILES), 256, 0, stream>>>(Abf, WeT, token_list,
                                                           tile_desc, n_tiles, out);
}

// Round 3
// 109.925 us; speedup vs baseline: 1.4002x; 1.2938x over previous
//
#include <hip/hip_runtime.h>
#include <hip/hip_bf16.h>
#include <stdint.h>

#define NTOK 8192
#define D_   1024
#define E_   8
#define MT   64
#define NT   128
#define BK   64
#define KK   2048
#define KSTEPS 32
#define MAX_TILES 192
#define BUF_S 12288   // shorts per LDS buffer: A 4096 + B 8192

typedef __attribute__((ext_vector_type(8))) short short8;
typedef __attribute__((ext_vector_type(4))) float f32x4;

__device__ inline unsigned short f2b(float f) {
    unsigned int u = __float_as_uint(f);
    unsigned int r = (u + 0x7fffu + ((u >> 16) & 1u)) >> 16;
    return (unsigned short)r;
}

__device__ inline uint4 pack8(float4 a, float4 b, float s) {
    return make_uint4(
        (unsigned)f2b(a.x * s) | ((unsigned)f2b(a.y * s) << 16),
        (unsigned)f2b(a.z * s) | ((unsigned)f2b(a.w * s) << 16),
        (unsigned)f2b(b.x * s) | ((unsigned)f2b(b.y * s) << 16),
        (unsigned)f2b(b.z * s) | ((unsigned)f2b(b.w * s) << 16));
}

// async global->LDS, 16B per lane; LDS dest = wave-uniform base + lane*16.
__device__ inline void gload16(const void* g, void* l) {
    __builtin_amdgcn_global_load_lds(
        (const __attribute__((address_space(1))) unsigned int*)(uintptr_t)g,
        (__attribute__((address_space(3))) unsigned int*)(unsigned int)(uintptr_t)l,
        16, 0, 0);
}

// ---------------- Phase 0: We (E,D,D) f32 -> WeT (E,M,D) bf16 ----------------
__global__ __launch_bounds__(256) void we_transpose(const float* __restrict__ We,
                                                    unsigned short* __restrict__ WeT) {
    int e = blockIdx.z;
    int m0 = blockIdx.x * 64;
    int d0 = blockIdx.y * 64;
    __shared__ float tile[64][65];
    const float* src = We + ((size_t)e << 20);
    int t = threadIdx.x;
    int r = t >> 4, c4 = (t & 15) * 4;
    #pragma unroll
    for (int i = 0; i < 4; i++) {
        int d = r + i * 16;
        float4 v = *reinterpret_cast<const float4*>(src + (size_t)(d0 + d) * D_ + m0 + c4);
        tile[d][c4 + 0] = v.x; tile[d][c4 + 1] = v.y;
        tile[d][c4 + 2] = v.z; tile[d][c4 + 3] = v.w;
    }
    __syncthreads();
    int m = t >> 2, dq = (t & 3) * 16;
    unsigned int pack[8];
    #pragma unroll
    for (int j = 0; j < 16; j += 2) {
        pack[j >> 1] = (unsigned int)f2b(tile[dq + j][m]) |
                       ((unsigned int)f2b(tile[dq + j + 1][m]) << 16);
    }
    uint4* dst = reinterpret_cast<uint4*>(WeT + ((size_t)e << 20) + (size_t)(m0 + m) * D_ + d0 + dq);
    dst[0] = make_uint4(pack[0], pack[1], pack[2], pack[3]);
    dst[1] = make_uint4(pack[4], pack[5], pack[6], pack[7]);
}

// ---------------- Phase 1: fused gating + weighted bf16 cast ----------------
// Abf[tok][0:1024]    = bf16(x[tok] * wA)  (expert a = min(top2))
// Abf[tok][1024:2048] = bf16(x[tok] * wB)  (expert b = max(top2))
__global__ __launch_bounds__(256) void gate_cast(const float* __restrict__ x,
                                                 const float* __restrict__ Wg,
                                                 int* __restrict__ g_tok,
                                                 unsigned short* __restrict__ Abf) {
    int t = threadIdx.x;
    int wave = t >> 6, lane = t & 63;
    int tok = blockIdx.x * 4 + wave;
    const float* xr = x + (size_t)tok * D_;

    float acc[8] = {0.f, 0.f, 0.f, 0.f, 0.f, 0.f, 0.f, 0.f};
    for (int i = 0; i < 16; i++) {
        int d = i * 64 + lane;
        float xv = xr[d];
        float4 w0 = *reinterpret_cast<const float4*>(Wg + d * 8);
        float4 w1 = *reinterpret_cast<const float4*>(Wg + d * 8 + 4);
        acc[0] += xv * w0.x; acc[1] += xv * w0.y; acc[2] += xv * w0.z; acc[3] += xv * w0.w;
        acc[4] += xv * w1.x; acc[5] += xv * w1.y; acc[6] += xv * w1.z; acc[7] += xv * w1.w;
    }
    #pragma unroll
    for (int e = 0; e < 8; e++)
        #pragma unroll
        for (int off = 32; off > 0; off >>= 1)
            acc[e] += __shfl_xor(acc[e], off, 64);

    // all lanes hold full sums -> compute top-2 redundantly (uniform)
    float best = acc[0]; int bi = 0;
    #pragma unroll
    for (int e = 1; e < 8; e++) { if (acc[e] > best) { best = acc[e]; bi = e; } }
    float second = -3.4e38f; int si = 0;
    #pragma unroll
    for (int e = 0; e < 8; e++) { if (e != bi && acc[e] > second) { second = acc[e]; si = e; } }
    float eb = __expf(second - best);
    float w0 = 1.f / (1.f + eb);
    float w1 = eb / (1.f + eb);
    int ea, ebx; float wA, wB;
    if (bi < si) { ea = bi; ebx = si; wA = w0; wB = w1; }
    else         { ea = si; ebx = bi; wA = w1; wB = w0; }
    if (lane == 0) g_tok[tok] = ea * 8 + ebx;

    // weighted cast, both halves; lane owns 16 contiguous elements
    const float4* xv4 = reinterpret_cast<const float4*>(xr + lane * 16);
    float4 v0 = xv4[0], v1 = xv4[1], v2 = xv4[2], v3 = xv4[3];
    unsigned short* rowp = Abf + (size_t)tok * KK + lane * 16;
    *reinterpret_cast<uint4*>(rowp)          = pack8(v0, v1, wA);
    *reinterpret_cast<uint4*>(rowp + 8)      = pack8(v2, v3, wA);
    *reinterpret_cast<uint4*>(rowp + 1024)   = pack8(v0, v1, wB);
    *reinterpret_cast<uint4*>(rowp + 1032)   = pack8(v2, v3, wB);
}

// ---------------- Phase 2: routing (bucket by expert pair + tile schedule) ----------------
__global__ __launch_bounds__(1024) void route_kernel(const int* __restrict__ g_tok,
                                                     int* __restrict__ token_list,
                                                     int4* __restrict__ tile_desc,
                                                     int* __restrict__ n_tiles_out) {
    __shared__ int cnt[64], pos[64], start[64];
    int t = threadIdx.x;
    if (t < 64) cnt[t] = 0;
    __syncthreads();
    for (int i = t; i < NTOK; i += 1024) atomicAdd(&cnt[g_tok[i]], 1);
    __syncthreads();
    if (t == 0) {
        int run = 0, nt = 0;
        for (int g = 0; g < 64; g++) {
            start[g] = run;
            int c = cnt[g];
            int off = 0;
            while (off < c) {
                int rows = (c - off < MT) ? (c - off) : MT;
                tile_desc[nt++] = make_int4(run + off, rows, g >> 3, g & 7);
                off += MT;
            }
            run += c;
        }
        *n_tiles_out = nt;
    }
    __syncthreads();
    if (t < 64) pos[t] = start[t];
    __syncthreads();
    for (int i = t; i < NTOK; i += 1024) {
        int p = atomicAdd(&pos[g_tok[i]], 1);
        token_list[p] = i;
    }
}

// ---------------- Phase 3: grouped GEMM — 3-deep pipeline, counted vmcnt, XOR swizzle ----------------
__global__ __launch_bounds__(256, 2) void moe_gemm(const unsigned short* __restrict__ Abf,
                                                   const unsigned short* __restrict__ WeT,
                                                   const int* __restrict__ token_list,
                                                   const int4* __restrict__ tile_desc,
                                                   const int* __restrict__ n_tiles,
                                                   float* __restrict__ out) {
    int tile = blockIdx.y;
    if (tile >= *n_tiles) return;
    int4 dsc = tile_desc[tile];
    int loff = dsc.x, rows = dsc.y, ea = dsc.z, ebx = dsc.w;
    int ncol0 = blockIdx.x * NT;

    __shared__ __align__(16) unsigned short lds[3 * BUF_S];  // 72 KB
    __shared__ int tokOut[MT];
    __shared__ int tokStage[MT];

    int t = threadIdx.x;
    int wave = t >> 6, lane = t & 63;

    if (t < MT) {
        int tk = token_list[loff + ((t < rows) ? t : 0)];
        tokStage[t] = tk;
        tokOut[t] = (t < rows) ? tk : -1;
    }
    __syncthreads();

    // per-thread staging sources (swizzle folded into global address; LDS dest stays linear)
    int swz8 = (((t & 7) ^ ((t >> 3) & 7)) << 3);
    const unsigned short* asrc0 = Abf + (size_t)tokStage[t >> 3] * KK + swz8;
    const unsigned short* asrc1 = Abf + (size_t)tokStage[32 + (t >> 3)] * KK + swz8;
    const unsigned short* wbase = WeT + ((size_t)ea << 20);
    size_t ebd = ((size_t)(ebx - ea)) << 20;
    const unsigned short* bsrc0 = wbase + (size_t)(ncol0 +  0 + (t >> 3)) * D_ + swz8;
    const unsigned short* bsrc1 = wbase + (size_t)(ncol0 + 32 + (t >> 3)) * D_ + swz8;
    const unsigned short* bsrc2 = wbase + (size_t)(ncol0 + 64 + (t >> 3)) * D_ + swz8;
    const unsigned short* bsrc3 = wbase + (size_t)(ncol0 + 96 + (t >> 3)) * D_ + swz8;

    int wu = wave * 512;   // wave-uniform LDS chunk base (shorts)
    auto stage = [&](int ks, int buf) {
        unsigned short* base = &lds[buf * BUF_S];
        int k0 = ks * BK;
        size_t eoff = (k0 < D_) ? (size_t)k0 : (size_t)(k0 - D_) + ebd;
        gload16(asrc0 + k0,   base + wu);
        gload16(asrc1 + k0,   base + 2048 + wu);
        gload16(bsrc0 + eoff, base + 4096 + wu);
        gload16(bsrc1 + eoff, base + 6144 + wu);
        gload16(bsrc2 + eoff, base + 8192 + wu);
        gload16(bsrc3 + eoff, base + 10240 + wu);
    };

    // wave grid 2(M) x 2(N); wave-tile 32x64
    int wm = (wave >> 1) * 32, wn = (wave & 1) * 64;
    int l15 = lane & 15, hi = lane >> 4, lo7 = lane & 7;
    int rA0 = (wm + l15) * BK;
    int rA1 = rA0 + 16 * BK;
    int cB0 = (wn + l15) * BK + 4096;
    int s0 = ((hi) ^ lo7) << 3;          // ksub 0 slot offset (shorts)
    int s1 = ((4 + hi) ^ lo7) << 3;      // ksub 1

    f32x4 acc[2][4];
    #pragma unroll
    for (int m = 0; m < 2; m++)
        #pragma unroll
        for (int n = 0; n < 4; n++) acc[m][n] = (f32x4){0.f, 0.f, 0.f, 0.f};

    stage(0, 0);
    stage(1, 1);
    int cur = 0;
    for (int ks = 0; ks < KSTEPS; ++ks) {
        if (ks < KSTEPS - 1) { asm volatile("s_waitcnt vmcnt(6)" ::: "memory"); }
        else                 { asm volatile("s_waitcnt vmcnt(0)" ::: "memory"); }
        __builtin_amdgcn_s_barrier();
        if (ks < KSTEPS - 2) {
            int b2 = cur + 2; if (b2 >= 3) b2 -= 3;
            stage(ks + 2, b2);
        }
        const unsigned short* Ab = &lds[cur * BUF_S];
        const unsigned short* Bb = Ab;  // B region at +4096, folded into cB
        #pragma unroll
        for (int ksub = 0; ksub < 2; ++ksub) {
            int s = ksub ? s1 : s0;
            short8 a0 = *reinterpret_cast<const short8*>(&Ab[rA0 + s]);
            short8 a1 = *reinterpret_cast<const short8*>(&Ab[rA1 + s]);
            #pragma unroll
            for (int n = 0; n < 4; n++) {
                short8 b = *reinterpret_cast<const short8*>(&Bb[cB0 + n * (16 * BK) + s]);
                acc[0][n] = __builtin_amdgcn_mfma_f32_16x16x32_bf16(a0, b, acc[0][n], 0, 0, 0);
                acc[1][n] = __builtin_amdgcn_mfma_f32_16x16x32_bf16(a1, b, acc[1][n], 0, 0, 0);
            }
        }
        cur = (cur == 2) ? 0 : cur + 1;
    }

    // epilogue: single writer per out row, weights already folded in
    int q4 = hi * 4;
    #pragma unroll
    for (int m = 0; m < 2; m++) {
        #pragma unroll
        for (int n = 0; n < 4; n++) {
            int col = ncol0 + wn + n * 16 + l15;
            #pragma unroll
            for (int j = 0; j < 4; j++) {
                int r = wm + m * 16 + q4 + j;
                int tk = tokOut[r];
                if (tk >= 0) out[(size_t)tk * D_ + col] = acc[m][n][j];
            }
        }
    }
}

extern "C" void kernel_launch(void* const* d_in, const int* in_sizes, int n_in,
                              void* d_out, int out_size, void* d_ws, size_t ws_size,
                              hipStream_t stream) {
    const float* x  = (const float*)d_in[0];
    const float* Wg = (const float*)d_in[1];
    const float* We = (const float*)d_in[2];
    float* out = (float*)d_out;

    size_t off = 0;
    auto alloc = [&](size_t bytes) -> void* {
        void* p = (char*)d_ws + off;
        off += (bytes + 255) & ~(size_t)255;
        return p;
    };
    unsigned short* WeT  = (unsigned short*)alloc((size_t)E_ * 1024 * 1024 * 2);  // 16 MB
    unsigned short* Abf  = (unsigned short*)alloc((size_t)NTOK * KK * 2);         // 33.5 MB
    int*   g_tok      = (int*)  alloc(NTOK * 4);
    int*   token_list = (int*)  alloc(NTOK * 4);
    int4*  tile_desc  = (int4*) alloc(MAX_TILES * 16);
    int*   n_tiles    = (int*)  alloc(4);

    we_transpose<<<dim3(16, 16, 8), 256, 0, stream>>>(We, WeT);
    gate_cast<<<NTOK / 4, 256, 0, stream>>>(x, Wg, g_tok, Abf);
    route_kernel<<<1, 1024, 0, stream>>>(g_tok, token_list, tile_desc, n_tiles);
    moe_gemm<<<dim3(D_ / NT, MAX_TILES), 256, 0, stream>>>(Abf, WeT, token_list,
                                                           tile_desc, n_tiles, out);
}